// Round 8
// baseline (306.175 us; speedup 1.0000x reference)
//
#include <hip/hip_runtime.h>
#include <hip/hip_bf16.h>

#define DIM   1024
#define NHEAD 16
#define HD    64
#define SEQ   4096

typedef __attribute__((ext_vector_type(4))) float  f32x4;
typedef __attribute__((ext_vector_type(8))) __bf16 bf16x8;
typedef __attribute__((ext_vector_type(4))) short  short4v;
typedef __attribute__((ext_vector_type(4))) unsigned uint4v;

// fp32 -> bf16 RNE
static __device__ __forceinline__ short f2bf(float f) {
  unsigned u = __builtin_bit_cast(unsigned, f);
  u += 0x7fffu + ((u >> 16) & 1u);
  return (short)(u >> 16);
}

// async global->LDS, 16B per lane
static __device__ __forceinline__ void gl2lds16(const void* g, void* l) {
  __builtin_amdgcn_global_load_lds(
      (__attribute__((address_space(1))) void*)g,
      (__attribute__((address_space(3))) void*)l, 16, 0, 0);
}

// One kernel casts x + the 4 weight matrices (weights land contiguously at wb).
__global__ void cast_all_kernel(const float* __restrict__ x,
                                const float* __restrict__ Wq,
                                const float* __restrict__ Wk,
                                const float* __restrict__ Wv,
                                const float* __restrict__ Wo,
                                short* __restrict__ xb,
                                short* __restrict__ wb) {
  int b = blockIdx.x;  // 8192 blocks, each covers 1024 floats
  const float* src;
  short* dst;
  if (b < 4096) {
    src = x + (size_t)b * 1024;
    dst = xb + (size_t)b * 1024;
  } else {
    int t = b - 4096;
    int w = t >> 10;
    size_t off = (size_t)(t & 1023) * 1024;
    src = (w == 0 ? Wq : w == 1 ? Wk : w == 2 ? Wv : Wo) + off;
    dst = wb + (size_t)w * 1048576 + off;
  }
  int i = threadIdx.x;
  float4 v = ((const float4*)src)[i];
  short4v o;
  o.x = f2bf(v.x); o.y = f2bf(v.y); o.z = f2bf(v.z); o.w = f2bf(v.w);
  ((short4v*)dst)[i] = o;
}

// NT GEMM: C[M,N] = A[M,K] * B[N,K]^T ; A,B bf16 (as short), K-major both.
template <bool F32OUT>
__global__ __launch_bounds__(256, 2) void gemm_nt(const short* __restrict__ A,
                                                  const short* __restrict__ B,
                                                  void* __restrict__ Cv,
                                                  int M, int N, int K) {
  __shared__ short As[128 * 32];
  __shared__ short Bs[128 * 32];
  const int tid  = threadIdx.x;
  const int wave = tid >> 6;
  const int lane = tid & 63;
  const int quad = lane >> 4;
  const int l15  = lane & 15;
  const int wm = (wave >> 1) * 64;
  const int wn = (wave & 1) * 64;
  const int bm = blockIdx.y * 128;
  const int bn = blockIdx.x * 128;

  f32x4 acc[4][4];
#pragma unroll
  for (int i = 0; i < 4; ++i)
#pragma unroll
    for (int j = 0; j < 4; ++j) acc[i][j] = (f32x4){0.f, 0.f, 0.f, 0.f};

  for (int k0 = 0; k0 < K; k0 += 32) {
#pragma unroll
    for (int it = 0; it < 2; ++it) {
      int c   = it * 256 + wave * 64 + lane;
      int row = c >> 2;
      int ce  = (c & 3) * 8;
      gl2lds16(A + (size_t)(bm + row) * K + k0 + ce,
               As + (size_t)(it * 256 + wave * 64) * 8);
      gl2lds16(B + (size_t)(bn + row) * K + k0 + ce,
               Bs + (size_t)(it * 256 + wave * 64) * 8);
    }
    __syncthreads();

    bf16x8 af[4], bfr[4];
#pragma unroll
    for (int mt = 0; mt < 4; ++mt)
      af[mt] = *(const bf16x8*)&As[(wm + mt * 16 + l15) * 32 + quad * 8];
#pragma unroll
    for (int nt = 0; nt < 4; ++nt)
      bfr[nt] = *(const bf16x8*)&Bs[(wn + nt * 16 + l15) * 32 + quad * 8];
#pragma unroll
    for (int mt = 0; mt < 4; ++mt)
#pragma unroll
      for (int nt = 0; nt < 4; ++nt)
        acc[mt][nt] = __builtin_amdgcn_mfma_f32_16x16x32_bf16(
            af[mt], bfr[nt], acc[mt][nt], 0, 0, 0);
    __syncthreads();
  }

  if (F32OUT) {
    float* C = (float*)Cv;
#pragma unroll
    for (int mt = 0; mt < 4; ++mt)
#pragma unroll
      for (int nt = 0; nt < 4; ++nt)
#pragma unroll
        for (int r = 0; r < 4; ++r)
          C[(size_t)(bm + wm + mt * 16 + quad * 4 + r) * N + bn + wn + nt * 16 + l15] =
              acc[mt][nt][r];
  } else {
    short* C = (short*)Cv;
#pragma unroll
    for (int mt = 0; mt < 4; ++mt)
#pragma unroll
      for (int nt = 0; nt < 4; ++nt)
#pragma unroll
        for (int r = 0; r < 4; ++r)
          C[(size_t)(bm + wm + mt * 16 + quad * 4 + r) * N + bn + wn + nt * 16 + l15] =
              f2bf(acc[mt][nt][r]);
  }
}

// Zero the fp32 O-accumulator (two 8MB segments) + l accumulator (256 KB).
__global__ void zero_ws_kernel(float* __restrict__ accO0,
                               float* __restrict__ accO1,
                               float* __restrict__ lp) {
  int b = blockIdx.x;
  float4 zz = {0.f, 0.f, 0.f, 0.f};
  if (b < 2048)
    ((float4*)accO0)[(size_t)b * 256 + threadIdx.x] = zz;
  else if (b < 4096)
    ((float4*)accO1)[(size_t)(b - 2048) * 256 + threadIdx.x] = zz;
  else
    ((float4*)lp)[(size_t)(b - 4096) * 256 + threadIdx.x] = zz;
}

// Flash attention, causal, LDS-free, key-split KS=4 (jt mod 4) with fp32
// ATOMIC accumulation. Fixed-max softmax exp2(s*SC-12) has no per-split max,
// so partial O and l over disjoint key sets simply ADD — each split wave
// atomicAdd's its unnormalized fp32 O-tile and l into zeroed accumulators;
// normalize_kernel divides at the end. Max chain = 16 tiles; grid 2048 blocks
// = 8/CU (4 resident + 4 backfill, longest-first: y = 31-(bb>>6)).
// Addressing: per-lane offsets computed once, per-step advance is a
// wave-uniform scalar pointer add (saddr-form loads, ~0 VALU).
// K prefetch uses TWO STATICALLY-NAMED register buffers (ka/kb); NEVER index
// a frag buffer with a runtime value (round 5: scratch spill, 552 MB).
// __launch_bounds__(256,2): (256,4) spilled. Keep at 2.
// GUARD z<=jtmax around the do-while AND epilogue (round 6 failure mode).
__global__ __launch_bounds__(256, 2) void flash_attn(const short* __restrict__ QK,
                                                     const short* __restrict__ Vt,
                                                     float* __restrict__ accO0,
                                                     float* __restrict__ accO1,
                                                     float* __restrict__ lp) {
  const int bb   = blockIdx.x;
  const int z    = bb & 3;              // key split: jt ≡ z (mod 4)
  const int h    = (bb >> 2) & 15;
  const int y    = 31 - (bb >> 6);      // longest first
  const int wave = threadIdx.x >> 6;
  const int lane = threadIdx.x & 63;
  const int quad = lane >> 4;
  const int l15  = lane & 15;

  const int qlo   = y * 128 + wave * 32;     // this wave's 32 q rows
  const int jtmax = (qlo + 31) >> 6;

  const short* Qp = QK + h * HD;
  const short* Kp = QK + 1024 + h * HD;
  const short* Vp = Vt + (size_t)(h * HD) * SEQ;

  if (z > jtmax) return;  // REQUIRED: do-while below; this split has 0 tiles

  bf16x8 qf[2][2];
#pragma unroll
  for (int s = 0; s < 2; ++s)
#pragma unroll
    for (int kk = 0; kk < 2; ++kk)
      qf[s][kk] = *(const bf16x8*)&Qp[(size_t)(qlo + s * 16 + l15) * 2048 +
                                      kk * 32 + quad * 8];

  f32x4 oacc[2][4];
  f32x4 lacc[2];
#pragma unroll
  for (int s = 0; s < 2; ++s) {
    lacc[s] = (f32x4){0.f, 0.f, 0.f, 0.f};
#pragma unroll
    for (int nt = 0; nt < 4; ++nt) oacc[s][nt] = (f32x4){0.f, 0.f, 0.f, 0.f};
  }

  const float SC = 0.125f * 1.44269504088896340736f;  // /sqrt(64) * log2(e)
  const int lrow = (l15 >> 2) * 8 + (l15 & 3);        // permuted K-row for A-frag

  bf16x8 onesb;
  { uint4v o1 = {0x3F803F80u, 0x3F803F80u, 0x3F803F80u, 0x3F803F80u};
    onesb = __builtin_bit_cast(bf16x8, o1); }

  // per-lane load offsets (loop-invariant); bases advance by scalar adds
  int koff[4], voff[4];
#pragma unroll
  for (int mt = 0; mt < 4; ++mt)
    koff[mt] = ((mt >> 1) * 32 + (mt & 1) * 4 + lrow) * 2048 + quad * 8;
#pragma unroll
  for (int nt = 0; nt < 4; ++nt)
    voff[nt] = (nt * 16 + l15) * SEQ + quad * 8;

  const int KADV = 4 * 64 * 2048;  // shorts per step (4 tiles of 64 K-rows)
  const int VADV = 4 * 64;         // shorts per step along the key axis

  auto loadK = [&](const short* kc, bf16x8 (&kf)[4][2]) {
#pragma unroll
    for (int mt = 0; mt < 4; ++mt) {
      kf[mt][0] = *(const bf16x8*)(kc + koff[mt]);
      kf[mt][1] = *(const bf16x8*)(kc + koff[mt] + 32);
    }
  };

  auto step = [&](int jt, const short* vc, const short* knext,
                  bf16x8 (&kf)[4][2], bf16x8 (&kn)[4][2]) {
    // ---- V frags issued first (consumed after exp — latency hidden)
    bf16x8 vf[2][4];
#pragma unroll
    for (int kk = 0; kk < 2; ++kk)
#pragma unroll
      for (int nt = 0; nt < 4; ++nt)
        vf[kk][nt] = *(const bf16x8*)(vc + voff[nt] + kk * 32);
    // ---- prefetch next K tile into the OTHER statically-named buffer
    if (jt + 4 <= jtmax) loadK(knext, kn);

    // ---- S^T = K·Q^T
    f32x4 sc[2][4];
#pragma unroll
    for (int mt = 0; mt < 4; ++mt) {
#pragma unroll
      for (int s = 0; s < 2; ++s) {
        sc[s][mt] = (f32x4){0.f, 0.f, 0.f, 0.f};
        sc[s][mt] = __builtin_amdgcn_mfma_f32_16x16x32_bf16(kf[mt][0], qf[s][0], sc[s][mt], 0, 0, 0);
        sc[s][mt] = __builtin_amdgcn_mfma_f32_16x16x32_bf16(kf[mt][1], qf[s][1], sc[s][mt], 0, 0, 0);
      }
    }

    // ---- p = exp2(s*SC - 12); causal mask on diagonal tile; pack bf16
    const bool domask = (jt == jtmax);
    unsigned pk[2][4][2];
#pragma unroll
    for (int s = 0; s < 2; ++s) {
      const int qv = qlo + s * 16 + l15;
#pragma unroll
      for (int mt = 0; mt < 4; ++mt) {
        float pr[4];
#pragma unroll
        for (int r = 0; r < 4; ++r) pr[r] = fmaf(sc[s][mt][r], SC, -12.0f);
        if (domask) {
          int kb0 = jt * 64 + (mt >> 1) * 32 + quad * 8 + (mt & 1) * 4;
#pragma unroll
          for (int r = 0; r < 4; ++r)
            if (kb0 + r > qv) pr[r] = -1e30f;
        }
#pragma unroll
        for (int r = 0; r < 4; ++r) pr[r] = exp2f(pr[r]);
        unsigned u0 = __builtin_bit_cast(unsigned, pr[0]) + 0x8000u;
        unsigned u1 = __builtin_bit_cast(unsigned, pr[1]) + 0x8000u;
        unsigned u2 = __builtin_bit_cast(unsigned, pr[2]) + 0x8000u;
        unsigned u3 = __builtin_bit_cast(unsigned, pr[3]) + 0x8000u;
        pk[s][mt][0] = __builtin_amdgcn_perm(u1, u0, 0x07060302u);
        pk[s][mt][1] = __builtin_amdgcn_perm(u3, u2, 0x07060302u);
      }
    }

    // ---- PV + ones-column row sums (C->A frag identity via key permutation)
#pragma unroll
    for (int kk = 0; kk < 2; ++kk) {
#pragma unroll
      for (int s = 0; s < 2; ++s) {
        bf16x8 pa;
        { uint4v t = {pk[s][2 * kk][0], pk[s][2 * kk][1],
                      pk[s][2 * kk + 1][0], pk[s][2 * kk + 1][1]};
          pa = __builtin_bit_cast(bf16x8, t); }
        lacc[s] = __builtin_amdgcn_mfma_f32_16x16x32_bf16(pa, onesb, lacc[s], 0, 0, 0);
#pragma unroll
        for (int nt = 0; nt < 4; ++nt)
          oacc[s][nt] = __builtin_amdgcn_mfma_f32_16x16x32_bf16(pa, vf[kk][nt], oacc[s][nt], 0, 0, 0);
      }
    }
  };

  {
    const short* kcur = Kp + z * (64 * 2048);
    const short* vcur = Vp + z * 64;
    bf16x8 ka[4][2], kb[4][2];
    loadK(kcur, ka);
    int jt = z;
    while (true) {
      step(jt, vcur, kcur + KADV, ka, kb);
      jt += 4; kcur += KADV; vcur += VADV;
      if (jt > jtmax) break;
      step(jt, vcur, kcur + KADV, kb, ka);
      jt += 4; kcur += KADV; vcur += VADV;
      if (jt > jtmax) break;
    }
  }

  // ---- epilogue: atomically accumulate fp32 partial O and l
#pragma unroll
  for (int s = 0; s < 2; ++s) {
    const int qz = qlo + s * 16;
    float* acc = (qz < 2048) ? accO0 : accO1;   // wave-uniform segment select
    const int qb = (qz < 2048) ? qz : qz - 2048;
#pragma unroll
    for (int nt = 0; nt < 4; ++nt)
#pragma unroll
      for (int r = 0; r < 4; ++r)
        atomicAdd(&acc[(size_t)(qb + quad * 4 + r) * DIM + h * HD + nt * 16 + l15],
                  oacc[s][nt][r]);
    if (l15 == 0) {
#pragma unroll
      for (int r = 0; r < 4; ++r)
        atomicAdd(&lp[(size_t)(qz + quad * 4 + r) * NHEAD + h], lacc[s][r]);
    }
  }
}

// Z[q][d] = accO[q][d] / l[q][h], cast to bf16. 8 elems/thread.
__global__ void normalize_kernel(const float* __restrict__ accO0,
                                 const float* __restrict__ accO1,
                                 const float* __restrict__ lp,
                                 short* __restrict__ Z) {
  size_t e = ((size_t)blockIdx.x * 256 + threadIdx.x) * 8;
  int q  = (int)(e >> 10);
  int hh = (int)((e & 1023) >> 6);
  float rinv = 1.0f / lp[(size_t)q * NHEAD + hh];
  const float* acc = (q < 2048) ? accO0 : (accO1 - (size_t)2048 * 1024);
  float4 a = *(const float4*)(acc + e);
  float4 b = *(const float4*)(acc + e + 4);
  uint4v o;
  float v0, v1;
  v0 = a.x * rinv; v1 = a.y * rinv;
  o[0] = (unsigned)(unsigned short)f2bf(v0) | ((unsigned)(unsigned short)f2bf(v1) << 16);
  v0 = a.z * rinv; v1 = a.w * rinv;
  o[1] = (unsigned)(unsigned short)f2bf(v0) | ((unsigned)(unsigned short)f2bf(v1) << 16);
  v0 = b.x * rinv; v1 = b.y * rinv;
  o[2] = (unsigned)(unsigned short)f2bf(v0) | ((unsigned)(unsigned short)f2bf(v1) << 16);
  v0 = b.z * rinv; v1 = b.w * rinv;
  o[3] = (unsigned)(unsigned short)f2bf(v0) | ((unsigned)(unsigned short)f2bf(v1) << 16);
  *(uint4v*)(Z + e) = o;
}

extern "C" void kernel_launch(void* const* d_in, const int* in_sizes, int n_in,
                              void* d_out, int out_size, void* d_ws, size_t ws_size,
                              hipStream_t stream) {
  const float* x  = (const float*)d_in[0];
  const float* Wq = (const float*)d_in[1];
  const float* Wk = (const float*)d_in[2];
  const float* Wv = (const float*)d_in[3];
  const float* Wo = (const float*)d_in[4];
  float* out = (float*)d_out;

  // 48 MB workspace, regions overlaid by lifetime:
  //  [0,8)   xb (cast->projs)            ; accO0 fp32 rows 0..2047 (zero->flash->norm)
  //  [8,12)  wq,wk (cast->QK proj)       ; lp fp32 [SEQ][NHEAD] at [8,8.25)
  //  [12,14) wv (cast->Vt proj)
  //  [14,16) wo (cast->final GEMM)
  //  [16,32) QKb (projs->flash)          ; Zb bf16 [16,24) (norm->final GEMM)
  //  [32,40) Vtb (proj->flash)
  //  [40,48) accO1 fp32 rows 2048..4095 (zero->flash->norm)
  char* ws   = (char*)d_ws;
  short* xb  = (short*)(ws);
  short* wqb = (short*)(ws + (size_t)8 * 1024 * 1024);
  short* wvb = wqb + 2 * 1024 * 1024;
  short* wob = wqb + 3 * 1024 * 1024;
  short* QKb = (short*)(ws + (size_t)16 * 1024 * 1024);
  short* Vtb = (short*)(ws + (size_t)32 * 1024 * 1024);
  float* accO0 = (float*)(ws);
  float* accO1 = (float*)(ws + (size_t)40 * 1024 * 1024);
  float* lpb   = (float*)(ws + (size_t)8 * 1024 * 1024);
  short* Zb    = QKb;  // over dead Q half of QKb after flash

  cast_all_kernel<<<dim3(8192), dim3(256), 0, stream>>>(x, Wq, Wk, Wv, Wo, xb, wqb);

  // fused Q+K projection: B = [Wq; Wk] (contiguous), C = QK [4096][2048]
  gemm_nt<false><<<dim3(16, 32), 256, 0, stream>>>(xb, wqb, QKb, SEQ, 2048, DIM);
  // V^T directly: C[d][s] = sum_k Wv[d][k] x[s][k]
  gemm_nt<false><<<dim3(32, 8), 256, 0, stream>>>(wvb, xb, Vtb, DIM, SEQ, DIM);

  zero_ws_kernel<<<dim3(4160), dim3(256), 0, stream>>>(accO0, accO1, lpb);
  flash_attn<<<dim3(2048), dim3(256), 0, stream>>>(QKb, Vtb, accO0, accO1, lpb);
  normalize_kernel<<<dim3(2048), dim3(256), 0, stream>>>(accO0, accO1, lpb, Zb);

  gemm_nt<true><<<dim3(8, 32), 256, 0, stream>>>(Zb, wob, out, SEQ, DIM, DIM);
}

// Round 10
// 275.341 us; speedup vs baseline: 1.1120x; 1.1120x over previous
//
#include <hip/hip_runtime.h>
#include <hip/hip_bf16.h>

#define DIM   1024
#define NHEAD 16
#define HD    64
#define SEQ   4096

typedef __attribute__((ext_vector_type(4))) float  f32x4;
typedef __attribute__((ext_vector_type(8))) __bf16 bf16x8;
typedef __attribute__((ext_vector_type(4))) short  short4v;
typedef __attribute__((ext_vector_type(4))) unsigned uint4v;

// fp32 -> bf16 RNE
static __device__ __forceinline__ short f2bf(float f) {
  unsigned u = __builtin_bit_cast(unsigned, f);
  u += 0x7fffu + ((u >> 16) & 1u);
  return (short)(u >> 16);
}

// async global->LDS, 16B per lane: per-lane GLOBAL gather, LDS dest =
// wave-uniform base + lane*16.
static __device__ __forceinline__ void gl2lds16(const void* g, void* l) {
  __builtin_amdgcn_global_load_lds(
      (__attribute__((address_space(1))) void*)g,
      (__attribute__((address_space(3))) void*)l, 16, 0, 0);
}

// One kernel casts x + the 4 weight matrices (weights land contiguously at wb).
__global__ void cast_all_kernel(const float* __restrict__ x,
                                const float* __restrict__ Wq,
                                const float* __restrict__ Wk,
                                const float* __restrict__ Wv,
                                const float* __restrict__ Wo,
                                short* __restrict__ xb,
                                short* __restrict__ wb) {
  int b = blockIdx.x;  // 8192 blocks, each covers 1024 floats
  const float* src;
  short* dst;
  if (b < 4096) {
    src = x + (size_t)b * 1024;
    dst = xb + (size_t)b * 1024;
  } else {
    int t = b - 4096;
    int w = t >> 10;
    size_t off = (size_t)(t & 1023) * 1024;
    src = (w == 0 ? Wq : w == 1 ? Wk : w == 2 ? Wv : Wo) + off;
    dst = wb + (size_t)w * 1048576 + off;
  }
  int i = threadIdx.x;
  float4 v = ((const float4*)src)[i];
  short4v o;
  o.x = f2bf(v.x); o.y = f2bf(v.y); o.z = f2bf(v.z); o.w = f2bf(v.w);
  ((short4v*)dst)[i] = o;
}

// NT GEMM: C[M,N] = A[M,K] * B[N,K]^T ; A,B bf16 (as short), K-major both.
template <bool F32OUT>
__global__ __launch_bounds__(256, 2) void gemm_nt(const short* __restrict__ A,
                                                  const short* __restrict__ B,
                                                  void* __restrict__ Cv,
                                                  int M, int N, int K) {
  __shared__ short As[128 * 32];
  __shared__ short Bs[128 * 32];
  const int tid  = threadIdx.x;
  const int wave = tid >> 6;
  const int lane = tid & 63;
  const int quad = lane >> 4;
  const int l15  = lane & 15;
  const int wm = (wave >> 1) * 64;
  const int wn = (wave & 1) * 64;
  const int bm = blockIdx.y * 128;
  const int bn = blockIdx.x * 128;

  f32x4 acc[4][4];
#pragma unroll
  for (int i = 0; i < 4; ++i)
#pragma unroll
    for (int j = 0; j < 4; ++j) acc[i][j] = (f32x4){0.f, 0.f, 0.f, 0.f};

  for (int k0 = 0; k0 < K; k0 += 32) {
#pragma unroll
    for (int it = 0; it < 2; ++it) {
      int c   = it * 256 + wave * 64 + lane;
      int row = c >> 2;
      int ce  = (c & 3) * 8;
      gl2lds16(A + (size_t)(bm + row) * K + k0 + ce,
               As + (size_t)(it * 256 + wave * 64) * 8);
      gl2lds16(B + (size_t)(bn + row) * K + k0 + ce,
               Bs + (size_t)(it * 256 + wave * 64) * 8);
    }
    __syncthreads();

    bf16x8 af[4], bfr[4];
#pragma unroll
    for (int mt = 0; mt < 4; ++mt)
      af[mt] = *(const bf16x8*)&As[(wm + mt * 16 + l15) * 32 + quad * 8];
#pragma unroll
    for (int nt = 0; nt < 4; ++nt)
      bfr[nt] = *(const bf16x8*)&Bs[(wn + nt * 16 + l15) * 32 + quad * 8];
#pragma unroll
    for (int mt = 0; mt < 4; ++mt)
#pragma unroll
      for (int nt = 0; nt < 4; ++nt)
        acc[mt][nt] = __builtin_amdgcn_mfma_f32_16x16x32_bf16(
            af[mt], bfr[nt], acc[mt][nt], 0, 0, 0);
    __syncthreads();
  }

  if (F32OUT) {
    float* C = (float*)Cv;
#pragma unroll
    for (int mt = 0; mt < 4; ++mt)
#pragma unroll
      for (int nt = 0; nt < 4; ++nt)
#pragma unroll
        for (int r = 0; r < 4; ++r)
          C[(size_t)(bm + wm + mt * 16 + quad * 4 + r) * N + bn + wn + nt * 16 + l15] =
              acc[mt][nt][r];
  } else {
    short* C = (short*)Cv;
#pragma unroll
    for (int mt = 0; mt < 4; ++mt)
#pragma unroll
      for (int nt = 0; nt < 4; ++nt)
#pragma unroll
        for (int r = 0; r < 4; ++r)
          C[(size_t)(bm + wm + mt * 16 + quad * 4 + r) * N + bn + wn + nt * 16 + l15] =
              f2bf(acc[mt][nt][r]);
  }
}

// Zero the fp32 O-accumulator (two 8MB segments) + l accumulator (256 KB).
__global__ void zero_ws_kernel(float* __restrict__ accO0,
                               float* __restrict__ accO1,
                               float* __restrict__ lp) {
  int b = blockIdx.x;
  float4 zz = {0.f, 0.f, 0.f, 0.f};
  if (b < 2048)
    ((float4*)accO0)[(size_t)b * 256 + threadIdx.x] = zz;
  else if (b < 4096)
    ((float4*)accO1)[(size_t)(b - 2048) * 256 + threadIdx.x] = zz;
  else
    ((float4*)lp)[(size_t)(b - 4096) * 256 + threadIdx.x] = zz;
}

// Flash attention, causal, key-split KS=4 with fp32 atomic accumulation.
// ROUND-8 LESSON: duration was pinned at ~7-9k cyc/wave-step by register-
// limited occupancy (~170 unified regs -> 2 waves/SIMD). This version cuts
// the footprint: 16 q rows/wave (halves qf/sc/oacc/pk) and K/V tiles staged
// in LDS via global_load_lds (kills the 64-reg kf/vf arrays).
// Block = 4 waves = 64 q rows [y*64, y*64+64); ALL waves share jtmax == y, so
// the per-step __syncthreads pair is wave-uniform. Dead splits (z > y) return
// before any barrier (block-uniform).
// LDS K layout: [chunk 8][slot 64][8 shorts]; slot s holds PERMUTED global
// row g(s) = ((s>>5)&1)*32+((s>>4)&1)*4+((s>>2)&3)*8+(s&3), so a lane's
// A-frag read is ds_read_b128 at slot mt*16+l15 (linear in l15 -> 2-way bank
// aliasing only, free). V layout: [chunk 8][d 64][8 shorts], natural order.
// Fixed-max softmax exp2(s*SC-12): no per-split max, partials ADD (atomics).
// NEVER index a frag buffer with a runtime value (round 5: scratch spill).
__global__ __launch_bounds__(256, 2) void flash_attn(const short* __restrict__ QK,
                                                     const short* __restrict__ Vt,
                                                     float* __restrict__ accO0,
                                                     float* __restrict__ accO1,
                                                     float* __restrict__ lp) {
  const int bb = blockIdx.x;
  const int z  = bb & 3;               // key split: jt ≡ z (mod 4)
  const int h  = (bb >> 2) & 15;
  const int y  = 63 - (bb >> 6);       // longest chains dispatched first
  if (z > y) return;                   // block-uniform: before any barrier

  __shared__ short Ks[8 * 64 * 8];     // 8 KB
  __shared__ short Vs[8 * 64 * 8];     // 8 KB

  const int wave = threadIdx.x >> 6;
  const int lane = threadIdx.x & 63;
  const int quad = lane >> 4;
  const int l15  = lane & 15;
  const int qlo  = y * 64 + wave * 16;   // this wave's 16 q rows

  const short* Qp = QK + h * HD;
  const short* Kp = QK + 1024 + h * HD;
  const short* Vp = Vt + (size_t)(h * HD) * SEQ;

  // Q frags (loaded once)
  bf16x8 qf0 = *(const bf16x8*)&Qp[(size_t)(qlo + l15) * 2048 + quad * 8];
  bf16x8 qf1 = *(const bf16x8*)&Qp[(size_t)(qlo + l15) * 2048 + 32 + quad * 8];

  f32x4 oacc[4];
  f32x4 lacc = (f32x4){0.f, 0.f, 0.f, 0.f};
#pragma unroll
  for (int nt = 0; nt < 4; ++nt) oacc[nt] = (f32x4){0.f, 0.f, 0.f, 0.f};

  const float SC = 0.125f * 1.44269504088896340736f;  // /sqrt(64) * log2(e)

  bf16x8 onesb;
  { uint4v o1 = {0x3F803F80u, 0x3F803F80u, 0x3F803F80u, 0x3F803F80u};
    onesb = __builtin_bit_cast(bf16x8, o1); }

  // staging: wave w fills chunks 2w, 2w+1 of each tile.
  // K slot permutation (see header comment):
  const int g = ((lane >> 5) & 1) * 32 + ((lane >> 4) & 1) * 4 +
                ((lane >> 2) & 3) * 8 + (lane & 3);
  const short* kstage = Kp + (size_t)(z * 64 + g) * 2048 + wave * 16;
  const short* vstage = Vp + (size_t)lane * SEQ + z * 64 + wave * 16;
  short* ksl = Ks + wave * 1024;       // chunk 2w base (512 shorts/chunk)
  short* vsl = Vs + wave * 1024;
  const size_t KADV = (size_t)4 * 64 * 2048;  // 4 tiles ahead (KS=4)
  const int    VADV = 4 * 64;

  for (int jt = z; jt <= y; jt += 4) {
    // ---- stage K,V tile via async DMA (4 instr/wave), then drain+barrier
    gl2lds16(kstage,     ksl);
    gl2lds16(kstage + 8, ksl + 512);
    gl2lds16(vstage,     vsl);
    gl2lds16(vstage + 8, vsl + 512);
    __syncthreads();   // compiler emits vmcnt(0) drain before s_barrier

    // ---- S^T = K·Q^T ; frags straight from LDS
    f32x4 sc[4];
#pragma unroll
    for (int mt = 0; mt < 4; ++mt) {
      bf16x8 k0 = *(const bf16x8*)&Ks[quad * 512 + (mt * 16 + l15) * 8];
      bf16x8 k1 = *(const bf16x8*)&Ks[(4 + quad) * 512 + (mt * 16 + l15) * 8];
      sc[mt] = (f32x4){0.f, 0.f, 0.f, 0.f};
      sc[mt] = __builtin_amdgcn_mfma_f32_16x16x32_bf16(k0, qf0, sc[mt], 0, 0, 0);
      sc[mt] = __builtin_amdgcn_mfma_f32_16x16x32_bf16(k1, qf1, sc[mt], 0, 0, 0);
    }

    // ---- p = exp2(s*SC - 12); causal mask only on the diagonal tile
    unsigned pk[4][2];
    const bool domask = (jt == y);     // wave-uniform
    const int qv = qlo + l15;
#pragma unroll
    for (int mt = 0; mt < 4; ++mt) {
      float pr[4];
#pragma unroll
      for (int r = 0; r < 4; ++r) pr[r] = fmaf(sc[mt][r], SC, -12.0f);
      if (domask) {
        int kb0 = jt * 64 + (mt >> 1) * 32 + quad * 8 + (mt & 1) * 4;
#pragma unroll
        for (int r = 0; r < 4; ++r)
          if (kb0 + r > qv) pr[r] = -1e30f;
      }
#pragma unroll
      for (int r = 0; r < 4; ++r) pr[r] = exp2f(pr[r]);
      unsigned u0 = __builtin_bit_cast(unsigned, pr[0]) + 0x8000u;
      unsigned u1 = __builtin_bit_cast(unsigned, pr[1]) + 0x8000u;
      unsigned u2 = __builtin_bit_cast(unsigned, pr[2]) + 0x8000u;
      unsigned u3 = __builtin_bit_cast(unsigned, pr[3]) + 0x8000u;
      pk[mt][0] = __builtin_amdgcn_perm(u1, u0, 0x07060302u);
      pk[mt][1] = __builtin_amdgcn_perm(u3, u2, 0x07060302u);
    }

    // ---- PV + ones-column row sums (C->A frag identity via key permutation)
#pragma unroll
    for (int kk = 0; kk < 2; ++kk) {
      bf16x8 pa;
      { uint4v t = {pk[2 * kk][0], pk[2 * kk][1],
                    pk[2 * kk + 1][0], pk[2 * kk + 1][1]};
        pa = __builtin_bit_cast(bf16x8, t); }
      lacc = __builtin_amdgcn_mfma_f32_16x16x32_bf16(pa, onesb, lacc, 0, 0, 0);
#pragma unroll
      for (int nt = 0; nt < 4; ++nt) {
        bf16x8 vb = *(const bf16x8*)&Vs[(kk * 4 + quad) * 512 + (nt * 16 + l15) * 8];
        oacc[nt] = __builtin_amdgcn_mfma_f32_16x16x32_bf16(pa, vb, oacc[nt], 0, 0, 0);
      }
    }
    __syncthreads();   // protect Ks/Vs before next step's DMA
    kstage += KADV;
    vstage += VADV;
  }

  // ---- epilogue: atomically accumulate fp32 partial O and l
  float* acc = (qlo < 2048) ? accO0 : accO1;   // wave-uniform segment select
  const int qb = (qlo < 2048) ? qlo : qlo - 2048;
#pragma unroll
  for (int nt = 0; nt < 4; ++nt)
#pragma unroll
    for (int r = 0; r < 4; ++r)
      atomicAdd(&acc[(size_t)(qb + quad * 4 + r) * DIM + h * HD + nt * 16 + l15],
                oacc[nt][r]);
  if (l15 == 0) {
#pragma unroll
    for (int r = 0; r < 4; ++r)
      atomicAdd(&lp[(size_t)(qlo + quad * 4 + r) * NHEAD + h], lacc[r]);
  }
}

// Z[q][d] = accO[q][d] / l[q][h], cast to bf16. 8 elems/thread.
__global__ void normalize_kernel(const float* __restrict__ accO0,
                                 const float* __restrict__ accO1,
                                 const float* __restrict__ lp,
                                 short* __restrict__ Z) {
  size_t e = ((size_t)blockIdx.x * 256 + threadIdx.x) * 8;
  int q  = (int)(e >> 10);
  int hh = (int)((e & 1023) >> 6);
  float rinv = 1.0f / lp[(size_t)q * NHEAD + hh];
  const float* acc = (q < 2048) ? accO0 : (accO1 - (size_t)2048 * 1024);
  float4 a = *(const float4*)(acc + e);
  float4 b = *(const float4*)(acc + e + 4);
  uint4v o;
  float v0, v1;
  v0 = a.x * rinv; v1 = a.y * rinv;
  o[0] = (unsigned)(unsigned short)f2bf(v0) | ((unsigned)(unsigned short)f2bf(v1) << 16);
  v0 = a.z * rinv; v1 = a.w * rinv;
  o[1] = (unsigned)(unsigned short)f2bf(v0) | ((unsigned)(unsigned short)f2bf(v1) << 16);
  v0 = b.x * rinv; v1 = b.y * rinv;
  o[2] = (unsigned)(unsigned short)f2bf(v0) | ((unsigned)(unsigned short)f2bf(v1) << 16);
  v0 = b.z * rinv; v1 = b.w * rinv;
  o[3] = (unsigned)(unsigned short)f2bf(v0) | ((unsigned)(unsigned short)f2bf(v1) << 16);
  *(uint4v*)(Z + e) = o;
}

extern "C" void kernel_launch(void* const* d_in, const int* in_sizes, int n_in,
                              void* d_out, int out_size, void* d_ws, size_t ws_size,
                              hipStream_t stream) {
  const float* x  = (const float*)d_in[0];
  const float* Wq = (const float*)d_in[1];
  const float* Wk = (const float*)d_in[2];
  const float* Wv = (const float*)d_in[3];
  const float* Wo = (const float*)d_in[4];
  float* out = (float*)d_out;

  // 48 MB workspace, regions overlaid by lifetime:
  //  [0,8)   xb (cast->projs)            ; accO0 fp32 rows 0..2047 (zero->flash->norm)
  //  [8,12)  wq,wk (cast->QK proj)       ; lp fp32 [SEQ][NHEAD] at [8,8.25)
  //  [12,14) wv (cast->Vt proj)
  //  [14,16) wo (cast->final GEMM)
  //  [16,32) QKb (projs->flash)          ; Zb bf16 [16,24) (norm->final GEMM)
  //  [32,40) Vtb (proj->flash)
  //  [40,48) accO1 fp32 rows 2048..4095 (zero->flash->norm)
  char* ws   = (char*)d_ws;
  short* xb  = (short*)(ws);
  short* wqb = (short*)(ws + (size_t)8 * 1024 * 1024);
  short* wvb = wqb + 2 * 1024 * 1024;
  short* wob = wqb + 3 * 1024 * 1024;
  short* QKb = (short*)(ws + (size_t)16 * 1024 * 1024);
  short* Vtb = (short*)(ws + (size_t)32 * 1024 * 1024);
  float* accO0 = (float*)(ws);
  float* accO1 = (float*)(ws + (size_t)40 * 1024 * 1024);
  float* lpb   = (float*)(ws + (size_t)8 * 1024 * 1024);
  short* Zb    = QKb;  // over dead Q half of QKb after flash

  cast_all_kernel<<<dim3(8192), dim3(256), 0, stream>>>(x, Wq, Wk, Wv, Wo, xb, wqb);

  // fused Q+K projection: B = [Wq; Wk] (contiguous), C = QK [4096][2048]
  gemm_nt<false><<<dim3(16, 32), 256, 0, stream>>>(xb, wqb, QKb, SEQ, 2048, DIM);
  // V^T directly: C[d][s] = sum_k Wv[d][k] x[s][k]
  gemm_nt<false><<<dim3(32, 8), 256, 0, stream>>>(wvb, xb, Vtb, DIM, SEQ, DIM);

  zero_ws_kernel<<<dim3(4160), dim3(256), 0, stream>>>(accO0, accO1, lpb);
  flash_attn<<<dim3(4096), dim3(256), 0, stream>>>(QKb, Vtb, accO0, accO1, lpb);
  normalize_kernel<<<dim3(2048), dim3(256), 0, stream>>>(accO0, accO1, lpb, Zb);

  gemm_nt<true><<<dim3(8, 32), 256, 0, stream>>>(Zb, wob, out, SEQ, DIM, DIM);
}

// Round 11
// 250.802 us; speedup vs baseline: 1.2208x; 1.0978x over previous
//
#include <hip/hip_runtime.h>
#include <hip/hip_bf16.h>

#define DIM   1024
#define NHEAD 16
#define HD    64
#define SEQ   4096

typedef __attribute__((ext_vector_type(4))) float  f32x4;
typedef __attribute__((ext_vector_type(8))) __bf16 bf16x8;
typedef __attribute__((ext_vector_type(4))) short  short4v;
typedef __attribute__((ext_vector_type(4))) unsigned uint4v;

// fp32 -> bf16 RNE
static __device__ __forceinline__ short f2bf(float f) {
  unsigned u = __builtin_bit_cast(unsigned, f);
  u += 0x7fffu + ((u >> 16) & 1u);
  return (short)(u >> 16);
}

// async global->LDS, 16B per lane: per-lane GLOBAL gather, LDS dest =
// wave-uniform base + lane*16.
static __device__ __forceinline__ void gl2lds16(const void* g, void* l) {
  __builtin_amdgcn_global_load_lds(
      (__attribute__((address_space(1))) void*)g,
      (__attribute__((address_space(3))) void*)l, 16, 0, 0);
}

// One kernel casts x + the 4 weight matrices (weights land contiguously at wb).
__global__ void cast_all_kernel(const float* __restrict__ x,
                                const float* __restrict__ Wq,
                                const float* __restrict__ Wk,
                                const float* __restrict__ Wv,
                                const float* __restrict__ Wo,
                                short* __restrict__ xb,
                                short* __restrict__ wb) {
  int b = blockIdx.x;  // 8192 blocks, each covers 1024 floats
  const float* src;
  short* dst;
  if (b < 4096) {
    src = x + (size_t)b * 1024;
    dst = xb + (size_t)b * 1024;
  } else {
    int t = b - 4096;
    int w = t >> 10;
    size_t off = (size_t)(t & 1023) * 1024;
    src = (w == 0 ? Wq : w == 1 ? Wk : w == 2 ? Wv : Wo) + off;
    dst = wb + (size_t)w * 1048576 + off;
  }
  int i = threadIdx.x;
  float4 v = ((const float4*)src)[i];
  short4v o;
  o.x = f2bf(v.x); o.y = f2bf(v.y); o.z = f2bf(v.z); o.w = f2bf(v.w);
  ((short4v*)dst)[i] = o;
}

// 128x128 NT GEMM tile body: C[M,N] = A[M,K]*B[N,K]^T, bf16 K-major inputs.
template <bool F32OUT>
static __device__ __forceinline__ void gemm_tile(const short* __restrict__ A,
                                                 const short* __restrict__ B,
                                                 void* __restrict__ Cv,
                                                 int N, int K, int bm, int bn,
                                                 short* As, short* Bs) {
  const int tid  = threadIdx.x;
  const int wave = tid >> 6;
  const int lane = tid & 63;
  const int quad = lane >> 4;
  const int l15  = lane & 15;
  const int wm = (wave >> 1) * 64;
  const int wn = (wave & 1) * 64;

  f32x4 acc[4][4];
#pragma unroll
  for (int i = 0; i < 4; ++i)
#pragma unroll
    for (int j = 0; j < 4; ++j) acc[i][j] = (f32x4){0.f, 0.f, 0.f, 0.f};

  for (int k0 = 0; k0 < K; k0 += 32) {
#pragma unroll
    for (int it = 0; it < 2; ++it) {
      int c   = it * 256 + wave * 64 + lane;
      int row = c >> 2;
      int ce  = (c & 3) * 8;
      gl2lds16(A + (size_t)(bm + row) * K + k0 + ce,
               As + (size_t)(it * 256 + wave * 64) * 8);
      gl2lds16(B + (size_t)(bn + row) * K + k0 + ce,
               Bs + (size_t)(it * 256 + wave * 64) * 8);
    }
    __syncthreads();

    bf16x8 af[4], bfr[4];
#pragma unroll
    for (int mt = 0; mt < 4; ++mt)
      af[mt] = *(const bf16x8*)&As[(wm + mt * 16 + l15) * 32 + quad * 8];
#pragma unroll
    for (int nt = 0; nt < 4; ++nt)
      bfr[nt] = *(const bf16x8*)&Bs[(wn + nt * 16 + l15) * 32 + quad * 8];
#pragma unroll
    for (int mt = 0; mt < 4; ++mt)
#pragma unroll
      for (int nt = 0; nt < 4; ++nt)
        acc[mt][nt] = __builtin_amdgcn_mfma_f32_16x16x32_bf16(
            af[mt], bfr[nt], acc[mt][nt], 0, 0, 0);
    __syncthreads();
  }

  if (F32OUT) {
    float* C = (float*)Cv;
#pragma unroll
    for (int mt = 0; mt < 4; ++mt)
#pragma unroll
      for (int nt = 0; nt < 4; ++nt)
#pragma unroll
        for (int r = 0; r < 4; ++r)
          C[(size_t)(bm + wm + mt * 16 + quad * 4 + r) * N + bn + wn + nt * 16 + l15] =
              acc[mt][nt][r];
  } else {
    short* C = (short*)Cv;
#pragma unroll
    for (int mt = 0; mt < 4; ++mt)
#pragma unroll
      for (int nt = 0; nt < 4; ++nt)
#pragma unroll
        for (int r = 0; r < 4; ++r)
          C[(size_t)(bm + wm + mt * 16 + quad * 4 + r) * N + bn + wn + nt * 16 + l15] =
              f2bf(acc[mt][nt][r]);
  }
}

// Generic NT GEMM (used for the final O-projection only).
template <bool F32OUT>
__global__ __launch_bounds__(256, 2) void gemm_nt(const short* __restrict__ A,
                                                  const short* __restrict__ B,
                                                  void* __restrict__ Cv,
                                                  int M, int N, int K) {
  __shared__ short As[128 * 32];
  __shared__ short Bs[128 * 32];
  gemm_tile<F32OUT>(A, B, Cv, N, K, blockIdx.y * 128, blockIdx.x * 128, As, Bs);
}

// Fused projection launch: blocks 0..511 compute QK = x·[Wq;Wk]^T
// ([4096][2048]); blocks 512..767 compute Vt = Wv·x^T ([1024][4096]).
// One launch -> tail overlap + better CU utilization than 512- and 256-block
// separate launches (the Vt GEMM alone ran at 1 block/CU).
__global__ __launch_bounds__(256, 2) void proj_kernel(const short* __restrict__ xb,
                                                      const short* __restrict__ wqk,
                                                      const short* __restrict__ wv,
                                                      short* __restrict__ QKb,
                                                      short* __restrict__ Vtb) {
  __shared__ short As[128 * 32];
  __shared__ short Bs[128 * 32];
  int b = blockIdx.x;
  if (b < 512) {
    gemm_tile<false>(xb, wqk, QKb, 2048, 1024, (b >> 4) * 128, (b & 15) * 128, As, Bs);
  } else {
    int t = b - 512;
    gemm_tile<false>(wv, xb, Vtb, 4096, 1024, (t >> 5) * 128, (t & 31) * 128, As, Bs);
  }
}

// Zero the fp32 O-accumulator (two 8MB segments) + l accumulator (256 KB).
__global__ void zero_ws_kernel(float* __restrict__ accO0,
                               float* __restrict__ accO1,
                               float* __restrict__ lp) {
  int b = blockIdx.x;
  float4 zz = {0.f, 0.f, 0.f, 0.f};
  if (b < 2048)
    ((float4*)accO0)[(size_t)b * 256 + threadIdx.x] = zz;
  else if (b < 4096)
    ((float4*)accO1)[(size_t)(b - 2048) * 256 + threadIdx.x] = zz;
  else
    ((float4*)lp)[(size_t)(b - 4096) * 256 + threadIdx.x] = zz;
}

// Flash attention, causal, key-split KS=4, fp32 atomic accumulation.
// ROUND-10 LESSON: 2 barriers per 64-key tile cost ~6k cyc of drain vs ~1.5k
// arithmetic. This version processes TWO 64-key subtiles (jt, jt+4) per
// barrier pair (32 KB LDS double-width staging) — barrier count halves, work
// per drain doubles. Block = 4 waves = 64 q rows; all waves share y,z so
// every barrier/branch is block-uniform. Dead splits (z>y) exit pre-barrier.
// LDS K layout per subtile: [chunk 8][slot 64][8 shorts], slot s holds
// permuted row g(s) (A-frag read = linear in l15, 2-way bank alias, free).
// Fixed-max softmax exp2(s*SC-12): no per-split max, partials ADD (atomics).
// NEVER index a frag/LDS-side register buffer with a runtime value (round 5
// scratch-spill lesson); subtile bases are compile-time constants (0/4096).
__global__ __launch_bounds__(256, 2) void flash_attn(const short* __restrict__ QK,
                                                     const short* __restrict__ Vt,
                                                     float* __restrict__ accO0,
                                                     float* __restrict__ accO1,
                                                     float* __restrict__ lp) {
  const int bb = blockIdx.x;
  const int z  = bb & 3;               // key split: jt ≡ z (mod 4)
  const int h  = (bb >> 2) & 15;
  const int y  = 63 - (bb >> 6);       // longest chains dispatched first
  if (z > y) return;                   // block-uniform: before any barrier

  __shared__ short Ks[2 * 4096];       // 16 KB: two 64-key subtiles
  __shared__ short Vs[2 * 4096];       // 16 KB

  const int wave = threadIdx.x >> 6;
  const int lane = threadIdx.x & 63;
  const int quad = lane >> 4;
  const int l15  = lane & 15;
  const int qlo  = y * 64 + wave * 16;   // this wave's 16 q rows

  const short* Qp = QK + h * HD;
  const short* Kp = QK + 1024 + h * HD;
  const short* Vp = Vt + (size_t)(h * HD) * SEQ;

  // Q frags (loaded once)
  bf16x8 qf0 = *(const bf16x8*)&Qp[(size_t)(qlo + l15) * 2048 + quad * 8];
  bf16x8 qf1 = *(const bf16x8*)&Qp[(size_t)(qlo + l15) * 2048 + 32 + quad * 8];

  f32x4 oacc[4];
  f32x4 lacc = (f32x4){0.f, 0.f, 0.f, 0.f};
#pragma unroll
  for (int nt = 0; nt < 4; ++nt) oacc[nt] = (f32x4){0.f, 0.f, 0.f, 0.f};

  const float SC = 0.125f * 1.44269504088896340736f;  // /sqrt(64) * log2(e)

  bf16x8 onesb;
  { uint4v o1 = {0x3F803F80u, 0x3F803F80u, 0x3F803F80u, 0x3F803F80u};
    onesb = __builtin_bit_cast(bf16x8, o1); }

  // staging: wave w fills chunks 2w, 2w+1 of each subtile.
  const int g = ((lane >> 5) & 1) * 32 + ((lane >> 4) & 1) * 4 +
                ((lane >> 2) & 3) * 8 + (lane & 3);
  const short* kstage = Kp + (size_t)(z * 64 + g) * 2048 + wave * 16;
  const short* vstage = Vp + (size_t)lane * SEQ + z * 64 + wave * 16;
  short* ksl = Ks + wave * 1024;       // chunk 2w base (512 shorts/chunk)
  short* vsl = Vs + wave * 1024;
  const size_t KSUB = (size_t)4 * 64 * 2048;  // subtile B: 4 tiles ahead
  const size_t KADV = 2 * KSUB;               // loop stride: 8 tiles
  const int    VSUB = 4 * 64;
  const int    VADV = 2 * VSUB;

  // one 64-key subtile: S^T=K·Q^T -> exp2 -> PV (+ones row-sum)
  auto subtile = [&](int jtc, int base) {
    f32x4 sc[4];
#pragma unroll
    for (int mt = 0; mt < 4; ++mt) {
      bf16x8 k0 = *(const bf16x8*)&Ks[base + quad * 512 + (mt * 16 + l15) * 8];
      bf16x8 k1 = *(const bf16x8*)&Ks[base + (4 + quad) * 512 + (mt * 16 + l15) * 8];
      sc[mt] = (f32x4){0.f, 0.f, 0.f, 0.f};
      sc[mt] = __builtin_amdgcn_mfma_f32_16x16x32_bf16(k0, qf0, sc[mt], 0, 0, 0);
      sc[mt] = __builtin_amdgcn_mfma_f32_16x16x32_bf16(k1, qf1, sc[mt], 0, 0, 0);
    }

    unsigned pk[4][2];
    const bool domask = (jtc == y);    // wave-uniform
    const int qv = qlo + l15;
#pragma unroll
    for (int mt = 0; mt < 4; ++mt) {
      float pr[4];
#pragma unroll
      for (int r = 0; r < 4; ++r) pr[r] = fmaf(sc[mt][r], SC, -12.0f);
      if (domask) {
        int kb0 = jtc * 64 + (mt >> 1) * 32 + quad * 8 + (mt & 1) * 4;
#pragma unroll
        for (int r = 0; r < 4; ++r)
          if (kb0 + r > qv) pr[r] = -1e30f;
      }
#pragma unroll
      for (int r = 0; r < 4; ++r) pr[r] = exp2f(pr[r]);
      unsigned u0 = __builtin_bit_cast(unsigned, pr[0]) + 0x8000u;
      unsigned u1 = __builtin_bit_cast(unsigned, pr[1]) + 0x8000u;
      unsigned u2 = __builtin_bit_cast(unsigned, pr[2]) + 0x8000u;
      unsigned u3 = __builtin_bit_cast(unsigned, pr[3]) + 0x8000u;
      pk[mt][0] = __builtin_amdgcn_perm(u1, u0, 0x07060302u);
      pk[mt][1] = __builtin_amdgcn_perm(u3, u2, 0x07060302u);
    }

#pragma unroll
    for (int kk = 0; kk < 2; ++kk) {
      bf16x8 pa;
      { uint4v t = {pk[2 * kk][0], pk[2 * kk][1],
                    pk[2 * kk + 1][0], pk[2 * kk + 1][1]};
        pa = __builtin_bit_cast(bf16x8, t); }
      lacc = __builtin_amdgcn_mfma_f32_16x16x32_bf16(pa, onesb, lacc, 0, 0, 0);
#pragma unroll
      for (int nt = 0; nt < 4; ++nt) {
        bf16x8 vb = *(const bf16x8*)&Vs[base + (kk * 4 + quad) * 512 + (nt * 16 + l15) * 8];
        oacc[nt] = __builtin_amdgcn_mfma_f32_16x16x32_bf16(pa, vb, oacc[nt], 0, 0, 0);
      }
    }
  };

  for (int jt = z; jt <= y; jt += 8) {
    const bool haveB = (jt + 4 <= y);  // block-uniform
    // ---- stage subtile A (and B if valid) via async DMA, then drain+barrier
    gl2lds16(kstage,     ksl);
    gl2lds16(kstage + 8, ksl + 512);
    gl2lds16(vstage,     vsl);
    gl2lds16(vstage + 8, vsl + 512);
    if (haveB) {
      gl2lds16(kstage + KSUB,     ksl + 4096);
      gl2lds16(kstage + KSUB + 8, ksl + 4096 + 512);
      gl2lds16(vstage + VSUB,     vsl + 4096);
      gl2lds16(vstage + VSUB + 8, vsl + 4096 + 512);
    }
    __syncthreads();   // vmcnt(0) drain + barrier

    subtile(jt, 0);
    if (haveB) subtile(jt + 4, 4096);

    __syncthreads();   // protect Ks/Vs before next step's DMA
    kstage += KADV;
    vstage += VADV;
  }

  // ---- epilogue: atomically accumulate fp32 partial O and l
  float* acc = (qlo < 2048) ? accO0 : accO1;   // wave-uniform segment select
  const int qb = (qlo < 2048) ? qlo : qlo - 2048;
#pragma unroll
  for (int nt = 0; nt < 4; ++nt)
#pragma unroll
    for (int r = 0; r < 4; ++r)
      atomicAdd(&acc[(size_t)(qb + quad * 4 + r) * DIM + h * HD + nt * 16 + l15],
                oacc[nt][r]);
  if (l15 == 0) {
#pragma unroll
    for (int r = 0; r < 4; ++r)
      atomicAdd(&lp[(size_t)(qlo + quad * 4 + r) * NHEAD + h], lacc[r]);
  }
}

// Z[q][d] = accO[q][d] / l[q][h], cast to bf16. 8 elems/thread.
__global__ void normalize_kernel(const float* __restrict__ accO0,
                                 const float* __restrict__ accO1,
                                 const float* __restrict__ lp,
                                 short* __restrict__ Z) {
  size_t e = ((size_t)blockIdx.x * 256 + threadIdx.x) * 8;
  int q  = (int)(e >> 10);
  int hh = (int)((e & 1023) >> 6);
  float rinv = 1.0f / lp[(size_t)q * NHEAD + hh];
  const float* acc = (q < 2048) ? accO0 : (accO1 - (size_t)2048 * 1024);
  float4 a = *(const float4*)(acc + e);
  float4 b = *(const float4*)(acc + e + 4);
  uint4v o;
  float v0, v1;
  v0 = a.x * rinv; v1 = a.y * rinv;
  o[0] = (unsigned)(unsigned short)f2bf(v0) | ((unsigned)(unsigned short)f2bf(v1) << 16);
  v0 = a.z * rinv; v1 = a.w * rinv;
  o[1] = (unsigned)(unsigned short)f2bf(v0) | ((unsigned)(unsigned short)f2bf(v1) << 16);
  v0 = b.x * rinv; v1 = b.y * rinv;
  o[2] = (unsigned)(unsigned short)f2bf(v0) | ((unsigned)(unsigned short)f2bf(v1) << 16);
  v0 = b.z * rinv; v1 = b.w * rinv;
  o[3] = (unsigned)(unsigned short)f2bf(v0) | ((unsigned)(unsigned short)f2bf(v1) << 16);
  *(uint4v*)(Z + e) = o;
}

extern "C" void kernel_launch(void* const* d_in, const int* in_sizes, int n_in,
                              void* d_out, int out_size, void* d_ws, size_t ws_size,
                              hipStream_t stream) {
  const float* x  = (const float*)d_in[0];
  const float* Wq = (const float*)d_in[1];
  const float* Wk = (const float*)d_in[2];
  const float* Wv = (const float*)d_in[3];
  const float* Wo = (const float*)d_in[4];
  float* out = (float*)d_out;

  // 48 MB workspace, regions overlaid by lifetime:
  //  [0,8)   xb (cast->projs)            ; accO0 fp32 rows 0..2047 (zero->flash->norm)
  //  [8,12)  wq,wk (cast->QK proj)       ; lp fp32 [SEQ][NHEAD] at [8,8.25)
  //  [12,14) wv (cast->Vt proj)
  //  [14,16) wo (cast->final GEMM)
  //  [16,32) QKb (projs->flash)          ; Zb bf16 [16,24) (norm->final GEMM)
  //  [32,40) Vtb (proj->flash)
  //  [40,48) accO1 fp32 rows 2048..4095 (zero->flash->norm)
  char* ws   = (char*)d_ws;
  short* xb  = (short*)(ws);
  short* wqb = (short*)(ws + (size_t)8 * 1024 * 1024);
  short* wvb = wqb + 2 * 1024 * 1024;
  short* wob = wqb + 3 * 1024 * 1024;
  short* QKb = (short*)(ws + (size_t)16 * 1024 * 1024);
  short* Vtb = (short*)(ws + (size_t)32 * 1024 * 1024);
  float* accO0 = (float*)(ws);
  float* accO1 = (float*)(ws + (size_t)40 * 1024 * 1024);
  float* lpb   = (float*)(ws + (size_t)8 * 1024 * 1024);
  short* Zb    = QKb;  // over dead Q half of QKb after flash

  cast_all_kernel<<<dim3(8192), dim3(256), 0, stream>>>(x, Wq, Wk, Wv, Wo, xb, wqb);

  // fused Q+K projection (blocks 0..511) + V^T projection (blocks 512..767)
  proj_kernel<<<dim3(768), dim3(256), 0, stream>>>(xb, wqb, wvb, QKb, Vtb);

  zero_ws_kernel<<<dim3(4160), dim3(256), 0, stream>>>(accO0, accO1, lpb);
  flash_attn<<<dim3(4096), dim3(256), 0, stream>>>(QKb, Vtb, accO0, accO1, lpb);
  normalize_kernel<<<dim3(2048), dim3(256), 0, stream>>>(accO0, accO1, lpb, Zb);

  gemm_nt<true><<<dim3(8, 32), 256, 0, stream>>>(Zb, wob, out, SEQ, DIM, DIM);
}